// Round 11
// baseline (448.967 us; speedup 1.0000x reference)
//
#include <hip/hip_runtime.h>

// MaxCutScoreNet: 12-layer delta-GCN + MLP head on N=50000 nodes, E=1.6M edges.
// R17: partition-major "bucket-row" space. br=(r&7)*6272+(r>>3); edge cols
//      PRE-MAPPED (u16, PAD_N=50176<65536); p=blockIdx&7 -> XCD-local ecw slice.
// R21: build = partitioned + LDS ballot-compaction + gemm0 front blocks.
// R22-R24: cooperative mega-kernel REFUTED (grid.sync ~140us across 8
//      non-coherent L2s). Split pipeline is correct.
// R25: degree-gated half-skip in spmm: only -7us (448 total) -> layers are
//      dispatch-overhead bound, not gather-bound (wave-level skip rate is
//      0.54^R, tiny for R=4/8). Build: FETCH 95MB at 1.9TB/s ~= 50us read
//      phase ~= atomic wall -> build = max(read, wall) + ramp.
// R28: (a) prep pre-packs cwe[i]=packcw(rowmap(src),f16(ew)) so build's 8
//      replicas read dst+cwe (12.8MB/replica vs 19.2) -> FETCH ~65MB, read
//      phase drops under the atomic wall. prep also zeroes cnt+ecw
//      (contiguous) so pad slots are 0 without wscale.
//      (b) wscale dispatch ELIMINATED: ecw stores raw ew; layer-1 spmm
//      scales inline (w = 2*dinv[br]*dinv[cm]*ew, fp32) and writes the
//      fp16-packed scaled halves back for layers 2-12. Write-back gating
//      exactly matches reader gating (half gated deg>32, tail deg>64).

constexpr int kN = 50000;
constexpr int kE = 1600000;
constexpr float kSelfW = -1.0f;   // 1 - DELTA, DELTA = 2.0
constexpr int kCAP = 72;          // bucket capacity; P(Poisson(32) >= 72) ~ 1e-8
constexpr int PAD_N = 50176;      // 8 * 6272
constexpr int kPROWS = PAD_N / 8; // 6272 bucket rows per partition
constexpr int E4  = kE / 4;       // 400000 v4-groups
constexpr int E8B = (E4 + 511) / 512;  // 782 chunks of 2048 edges
constexpr int NBG = (kN + 255) / 256;  // 196 gemm0 blocks
// prep grid segments: [0,ZB) zero cnt+ecw; [ZB,ZB+PKB) pack cwe; rest Weff.
constexpr int ZB  = (PAD_N * 73) / 1024;      // 3577 (exact: PAD_N*73 = 3577*1024)
constexpr int PKB = (E4 + 255) / 256;          // 1563
constexpr int WFB = 17;                        // 129*32 elems / 256
constexpr int PREPG = ZB + PKB + WFB;          // 5157

typedef int      v4i __attribute__((ext_vector_type(4)));
typedef unsigned v4u __attribute__((ext_vector_type(4)));
typedef float    v4f __attribute__((ext_vector_type(4)));
typedef _Float16 h8v __attribute__((ext_vector_type(8)));

__device__ __forceinline__ int rowmap(int r) {  // original row -> bucket row
  return (r & 7) * kPROWS + (r >> 3);
}
__device__ __forceinline__ unsigned packcw(int colMapped, float w) {
  _Float16 h = (_Float16)w;
  unsigned short u;
  __builtin_memcpy(&u, &h, 2);
  return (unsigned)(unsigned short)colMapped | ((unsigned)u << 16);
}
__device__ __forceinline__ float unpw(unsigned e) {
  unsigned short u = (unsigned short)(e >> 16);
  _Float16 h;
  __builtin_memcpy(&h, &u, 2);
  return (float)h;
}
__device__ __forceinline__ unsigned pack2h(float a, float b) {
  _Float16 ha = (_Float16)a, hb = (_Float16)b;
  unsigned short ua, ub;
  __builtin_memcpy(&ua, &ha, 2);
  __builtin_memcpy(&ub, &hb, 2);
  return (unsigned)ua | ((unsigned)ub << 16);
}
__device__ __forceinline__ float fast_tanh(float x) {
  float t = __expf(2.0f * x);
  float r = __builtin_amdgcn_rcpf(t + 1.0f);
  return 1.0f - 2.0f * r;
}

// -- prep: zero cnt+ecw (contiguous, exact) + pack cwe + fold Weff/beff -----
__global__ __launch_bounds__(256)
void prep(int* __restrict__ cnt, const float* __restrict__ Wi,
          const float* __restrict__ bi, const float* __restrict__ Wc0,
          float* __restrict__ Weff, float* __restrict__ beff,
          const int* __restrict__ src, const float* __restrict__ ew,
          unsigned* __restrict__ cwe) {
  if (blockIdx.x < ZB) {
    // zero cnt (PAD_N u32) + ecw (PAD_N*72 u32): contiguous in workspace
    size_t i = (size_t)blockIdx.x * 1024 + threadIdx.x * 4;
    *reinterpret_cast<int4*>(cnt + i) = make_int4(0, 0, 0, 0);
  } else if (blockIdx.x < ZB + PKB) {
    int i = (blockIdx.x - ZB) * 256 + threadIdx.x;
    if (i >= E4) return;
    v4i s = reinterpret_cast<const v4i*>(src)[i];
    v4f w = reinterpret_cast<const v4f*>(ew)[i];
    v4u c;
    c.x = packcw(rowmap(s.x), w.x);
    c.y = packcw(rowmap(s.y), w.y);
    c.z = packcw(rowmap(s.z), w.z);
    c.w = packcw(rowmap(s.w), w.w);
    reinterpret_cast<v4u*>(cwe)[i] = c;
  } else {
    int idx = (blockIdx.x - ZB - PKB) * 256 + threadIdx.x;
    if (idx >= 129 * 32) return;
    int r = idx >> 5, j = idx & 31;
    float acc = 0.0f;
    if (r < 128) {
      for (int k = 0; k < 128; ++k) acc += Wi[r * 128 + k] * Wc0[k * 32 + j];
      Weff[r * 32 + j] = acc;
    } else {
      for (int k = 0; k < 128; ++k) acc += bi[k] * Wc0[k * 32 + j];
      beff[j] = acc;
    }
  }
}

// -- merged: gemm0 front blocks + partitioned compacted count/scatter -------
// Blocks [0, NBG): gemm0. Blocks [NBG, NBG+8*E8B): build; p=blockIdx&7
// (XCD residue -> ecw writes merge in one XCD's L2); 2048-edge chunk
// ballot-compacted to ~256 matching (cwe, row) pairs in LDS, then FULL
// waves issue dense global atomics + XCD-local ecw stores. Reads dst+cwe
// only (12.8MB/replica; cwe pre-packed by prep).
__global__ __launch_bounds__(256)
void build_cnt_gemm0(const int* __restrict__ dst, const unsigned* __restrict__ cwe,
                     int* __restrict__ cnt, unsigned* __restrict__ ecw,
                     const float* __restrict__ X,
                     const float* __restrict__ Weff,
                     const float* __restrict__ beff,
                     _Float16* __restrict__ Y, int e4, int n) {
  __shared__ unsigned s_buf[4128];   // 16.5KB; aliased by both branches
  if (blockIdx.x < NBG) {
    // ---------------- gemm0 front blocks ----------------
    float* smem = reinterpret_cast<float*>(s_buf);
    for (int idx = threadIdx.x; idx < 128 * 32; idx += 256) {
      int j = idx >> 7, k = idx & 127;
      smem[j * 128 + k] = Weff[k * 32 + j];   // stage transposed
    }
    if (threadIdx.x < 32) smem[4096 + threadIdx.x] = beff[threadIdx.x];
    __syncthreads();
    int row = blockIdx.x * 256 + threadIdx.x;
    if (row >= n) return;
    float acc[32];
#pragma unroll
    for (int j = 0; j < 32; ++j) acc[j] = smem[4096 + j];
    const float4* xr = reinterpret_cast<const float4*>(X + (size_t)row * 128);
    const float4* Ws4 = reinterpret_cast<const float4*>(smem);
    for (int k4 = 0; k4 < 32; ++k4) {
      float4 a = xr[k4];
#pragma unroll
      for (int j = 0; j < 32; ++j) {
        float4 wv = Ws4[j * 32 + k4];
        acc[j] += a.x * wv.x + a.y * wv.y + a.z * wv.z + a.w * wv.w;
      }
    }
    h8v* yr = reinterpret_cast<h8v*>(Y + (size_t)rowmap(row) * 32);
#pragma unroll
    for (int j8 = 0; j8 < 4; ++j8) {
      h8v v;
#pragma unroll
      for (int q = 0; q < 8; ++q) v[q] = (_Float16)acc[8 * j8 + q];
      yr[j8] = v;
    }
    return;
  }
  // ---------------- partitioned build blocks ----------------
  unsigned*       s_cw = s_buf;                                        // [2048]
  unsigned short* s_br = reinterpret_cast<unsigned short*>(s_buf + 2048); // [2048]
  int*            s_cnt = reinterpret_cast<int*>(s_buf + 3072);
  if (threadIdx.x == 0) *s_cnt = 0;
  __syncthreads();
  int b = blockIdx.x - NBG;
  int p = blockIdx.x & 7;           // partition == XCD residue (perf heuristic)
  int chunk = b >> 3;
  int lane = threadIdx.x & 63;
  int i0 = chunk * 512 + threadIdx.x;
  int i1 = i0 + 256;
  v4i dvA = {-1,-1,-1,-1}, dvB = {-1,-1,-1,-1};
  v4u cvA = {0,0,0,0},     cvB = {0,0,0,0};
  bool vA = i0 < e4, vB = i1 < e4;
  if (vA) {
    dvA = reinterpret_cast<const v4i*>(dst)[i0];
    cvA = reinterpret_cast<const v4u*>(cwe)[i0];
  }
  if (vB) {
    dvB = reinterpret_cast<const v4i*>(dst)[i1];
    cvB = reinterpret_cast<const v4u*>(cwe)[i1];
  }
#pragma unroll
  for (int g = 0; g < 2; ++g) {
    v4i dv = g ? dvB : dvA;
    v4u cv = g ? cvB : cvA;
    bool valid = g ? vB : vA;
#pragma unroll
    for (int c = 0; c < 4; ++c) {
      bool keep = valid && ((dv[c] & 7) == p);
      unsigned long long mask = __ballot(keep);
      int base = 0;
      int nb = __popcll(mask);
      if (lane == 0 && nb) base = atomicAdd(s_cnt, nb);   // LDS atomic, 1/wave
      base = __shfl(base, 0, 64);
      if (keep) {
        int pos = base + __popcll(mask & ((1ull << lane) - 1ull));
        s_cw[pos] = cv[c];
        s_br[pos] = (unsigned short)(dv[c] >> 3);
      }
    }
  }
  __syncthreads();
  int m = *s_cnt;                    // ~256 +- 16
  for (int t = threadIdx.x; t < m; t += 256) {
    int br = p * kPROWS + s_br[t];
    int r = atomicAdd(&cnt[br], 1);  // dense: full waves issue 64 ops/instr
    if (r < kCAP) ecw[(size_t)br * kCAP + r] = s_cw[t];  // XCD-local slice
  }
}

// ------- wave-per-bucket-row deg sum -> dinv[br] ---------------------------
__global__ __launch_bounds__(256)
void deg_dinv_wave(const int* __restrict__ cnt, const unsigned* __restrict__ ecw,
                   float* __restrict__ dinv) {
  int lane = threadIdx.x & 63;
  int br = blockIdx.x * 4 + (threadIdx.x >> 6);
  int deg = min(cnt[br], kCAP);
  size_t base = (size_t)br * kCAP;
  float d = 0.0f;
  for (int i = lane; i < deg; i += 64) d += unpw(ecw[base + i]);
#pragma unroll
  for (int off = 32; off > 0; off >>= 1) d += __shfl_xor(d, off, 64);
  if (lane == 0) dinv[br] = (d > 0.0f) ? rsqrtf(fmaxf(d, 1e-12f)) : 0.0f;
}

// ------ fused SpMM + self + bias + tanh (+ next GEMM or MLP head) ----------
// R=64/DOUT rows/wave, W=DOUT lanes/row, L=DOUT/8, S=8 subs. Half-skip:
// slots 0..31 unconditional; 32..63 gated deg>32; tail 64..71 gated deg>64.
// SC (layer 1 only): ecw holds raw ew; scale inline w=2*dinv[br]*dinv[cm]*ew
// (fp32) and write fp16-packed scaled halves back for layers 2-12. Write
// gating == read gating, so every slot later read is scaled exactly once.
template <int DOUT, int DNEXT, bool FINAL, bool SC>
__global__ __launch_bounds__(256)
void spmm_fused(const _Float16* __restrict__ HW, const int* __restrict__ cnt,
                unsigned* __restrict__ ecw, const float* __restrict__ dv,
                const float* __restrict__ b,
                const float* __restrict__ Wn, void* __restrict__ Out,
                const float* __restrict__ Wm0, const float* __restrict__ bm0,
                const float* __restrict__ Wm1, const float* __restrict__ bm1,
                const float* __restrict__ Wf, const float* __restrict__ bf,
                int n) {
  constexpr int R = 64 / DOUT;       // rows per wave (2 / 4 / 8)
  constexpr int W = DOUT;            // lanes per row
  constexpr int L = DOUT / 8;        // lanes per edge (4 / 2 / 1)
  constexpr int S = 8;               // subs per row
  constexpr int WST = DNEXT + 1;
  constexpr int JPT = (DNEXT > 0) ? (DNEXT / S) : 1;   // cols per lane
  __shared__ float smem[(DNEXT > 0) ? DOUT * WST : 448];
  if constexpr (DNEXT > 0) {
    for (int idx = threadIdx.x; idx < DOUT * DNEXT; idx += 256) {
      int k = idx / DNEXT, j = idx - k * DNEXT;
      smem[k * WST + j] = Wn[idx];
    }
    __syncthreads();
  }
  if constexpr (FINAL) {
    int t = threadIdx.x;
    if (t < 128) smem[t] = Wm0[t];          // w0: 8x16
    if (t < 256) smem[128 + t] = Wm1[t];    // w1: 16x16
    if (t < 16) {
      smem[384 + t] = bm0[t];
      smem[400 + t] = bm1[t];
      smem[416 + t] = Wf[t];
    }
    if (t == 0) smem[432] = bf[0];
    __syncthreads();
  }
  int lane = threadIdx.x & 63;
  int wid = threadIdx.x >> 6;
  int g = lane / W;                  // row-group (0..R-1)
  int gl = lane - g * W;
  int ch8 = gl & (L - 1);
  int sub = gl / L;                  // 0..7
  int p = blockIdx.x & 7;            // partition (XCD-local heuristic)
  int q = blockIdx.x >> 3;
  int brLocal = q * (4 * R) + wid * R + g;
  int br = p * kPROWS + brLocal;     // bucket row == hw row index
  int deg = min(cnt[br], kCAP);
  uint4* ecw4 = reinterpret_cast<uint4*>(ecw + (size_t)br * kCAP);
  const h8v* HW8 = reinterpret_cast<const h8v*>(HW);
  float dbr = 0.0f;
  if constexpr (SC) dbr = 2.0f * dv[br];
  uint4 ea = ecw4[sub];
  h8v a0 = HW8[(size_t)(ea.x & 0xFFFFu) * L + ch8];
  h8v a1 = HW8[(size_t)(ea.y & 0xFFFFu) * L + ch8];
  h8v a2 = HW8[(size_t)(ea.z & 0xFFFFu) * L + ch8];
  h8v a3 = HW8[(size_t)(ea.w & 0xFFFFu) * L + ch8];
  float wa0, wa1, wa2, wa3;
  if constexpr (SC) {
    wa0 = dbr * dv[ea.x & 0xFFFFu] * unpw(ea.x);
    wa1 = dbr * dv[ea.y & 0xFFFFu] * unpw(ea.y);
    wa2 = dbr * dv[ea.z & 0xFFFFu] * unpw(ea.z);
    wa3 = dbr * dv[ea.w & 0xFFFFu] * unpw(ea.w);
    ecw4[sub] = make_uint4(packcw(ea.x & 0xFFFFu, wa0), packcw(ea.y & 0xFFFFu, wa1),
                           packcw(ea.z & 0xFFFFu, wa2), packcw(ea.w & 0xFFFFu, wa3));
  } else {
    wa0 = unpw(ea.x); wa1 = unpw(ea.y); wa2 = unpw(ea.z); wa3 = unpw(ea.w);
  }
  float acc[8];
#pragma unroll
  for (int q8 = 0; q8 < 8; ++q8)
    acc[q8] = wa0 * (float)a0[q8] + wa1 * (float)a1[q8] +
              wa2 * (float)a2[q8] + wa3 * (float)a3[q8];
  if (deg > 32) {                    // ~46% of rows: second 32-slot half
    uint4 eb = ecw4[8 + sub];
    h8v b0 = HW8[(size_t)(eb.x & 0xFFFFu) * L + ch8];
    h8v b1 = HW8[(size_t)(eb.y & 0xFFFFu) * L + ch8];
    h8v b2 = HW8[(size_t)(eb.z & 0xFFFFu) * L + ch8];
    h8v b3 = HW8[(size_t)(eb.w & 0xFFFFu) * L + ch8];
    float wb0, wb1, wb2, wb3;
    if constexpr (SC) {
      wb0 = dbr * dv[eb.x & 0xFFFFu] * unpw(eb.x);
      wb1 = dbr * dv[eb.y & 0xFFFFu] * unpw(eb.y);
      wb2 = dbr * dv[eb.z & 0xFFFFu] * unpw(eb.z);
      wb3 = dbr * dv[eb.w & 0xFFFFu] * unpw(eb.w);
      ecw4[8 + sub] = make_uint4(packcw(eb.x & 0xFFFFu, wb0), packcw(eb.y & 0xFFFFu, wb1),
                                 packcw(eb.z & 0xFFFFu, wb2), packcw(eb.w & 0xFFFFu, wb3));
    } else {
      wb0 = unpw(eb.x); wb1 = unpw(eb.y); wb2 = unpw(eb.z); wb3 = unpw(eb.w);
    }
#pragma unroll
    for (int q8 = 0; q8 < 8; ++q8)
      acc[q8] += wb0 * (float)b0[q8] + wb1 * (float)b1[q8] +
                 wb2 * (float)b2[q8] + wb3 * (float)b3[q8];
    if (deg > 64) {                  // rare tail: slots 64..71 (subs 0,1)
      if (sub < 2) {
        uint4 et = ecw4[16 + sub];
        h8v t0 = HW8[(size_t)(et.x & 0xFFFFu) * L + ch8];
        h8v t1 = HW8[(size_t)(et.y & 0xFFFFu) * L + ch8];
        h8v t2 = HW8[(size_t)(et.z & 0xFFFFu) * L + ch8];
        h8v t3 = HW8[(size_t)(et.w & 0xFFFFu) * L + ch8];
        float u0, u1, u2, u3;
        if constexpr (SC) {
          u0 = dbr * dv[et.x & 0xFFFFu] * unpw(et.x);
          u1 = dbr * dv[et.y & 0xFFFFu] * unpw(et.y);
          u2 = dbr * dv[et.z & 0xFFFFu] * unpw(et.z);
          u3 = dbr * dv[et.w & 0xFFFFu] * unpw(et.w);
          ecw4[16 + sub] = make_uint4(packcw(et.x & 0xFFFFu, u0), packcw(et.y & 0xFFFFu, u1),
                                      packcw(et.z & 0xFFFFu, u2), packcw(et.w & 0xFFFFu, u3));
        } else {
          u0 = unpw(et.x); u1 = unpw(et.y); u2 = unpw(et.z); u3 = unpw(et.w);
        }
#pragma unroll
        for (int q8 = 0; q8 < 8; ++q8)
          acc[q8] += u0 * (float)t0[q8] + u1 * (float)t1[q8] +
                     u2 * (float)t2[q8] + u3 * (float)t3[q8];
      }
    }
  }
#pragma unroll
  for (int off = W / 2; off >= L; off >>= 1) {
#pragma unroll
    for (int q8 = 0; q8 < 8; ++q8) acc[q8] += __shfl_xor(acc[q8], off, 64);
  }
  int krow = 8 * ch8;
  h8v hsv = HW8[(size_t)br * L + ch8];
  float h[8];
#pragma unroll
  for (int q8 = 0; q8 < 8; ++q8)
    h[q8] = fast_tanh(acc[q8] + kSelfW * (float)hsv[q8] + b[krow + q8]);
  if constexpr (FINAL) {
    int row = (brLocal << 3) | p;    // inverse map for output
    if (gl == 0 && row < n) {
      float y0[16];
#pragma unroll
      for (int j = 0; j < 16; ++j) {
        float v = smem[384 + j];
#pragma unroll
        for (int k = 0; k < 8; ++k) v += h[k] * smem[k * 16 + j];
        y0[j] = fmaxf(v, 0.0f);
      }
      float y1[16];
#pragma unroll
      for (int j = 0; j < 16; ++j) {
        float v = smem[400 + j];
#pragma unroll
        for (int k = 0; k < 16; ++k) v += y0[k] * smem[128 + k * 16 + j];
        y1[j] = fmaxf(v, 0.0f);
      }
      float z = smem[432];
#pragma unroll
      for (int k = 0; k < 16; ++k) z += y1[k] * smem[416 + k];
      reinterpret_cast<float*>(Out)[row] = fast_tanh(z);
    }
  } else {
    float pj[JPT];
    int jbase = sub * JPT;
#pragma unroll
    for (int jj = 0; jj < JPT; ++jj) {
      int j = jbase + jj;
      float v = 0.0f;
#pragma unroll
      for (int q8 = 0; q8 < 8; ++q8) v += h[q8] * smem[(krow + q8) * WST + j];
      pj[jj] = v;
    }
#pragma unroll
    for (int off = 1; off < L; off <<= 1) {
#pragma unroll
      for (int jj = 0; jj < JPT; ++jj) pj[jj] += __shfl_xor(pj[jj], off, 64);
    }
    if (ch8 == 0) {                  // pad rows write into pad hw slots (ok)
      _Float16* op = reinterpret_cast<_Float16*>(Out) + (size_t)br * DNEXT + jbase;
      if constexpr (JPT == 4) {
        uint2 u = make_uint2(pack2h(pj[0], pj[1]), pack2h(pj[2], pj[3]));
        *reinterpret_cast<uint2*>(op) = u;
      } else if constexpr (JPT == 2) {
        *reinterpret_cast<unsigned*>(op) = pack2h(pj[0], pj[1]);
      } else {
        op[0] = (_Float16)pj[0];
      }
    }
  }
}

// ---------------- launch ----------------
extern "C" void kernel_launch(void* const* d_in, const int* in_sizes, int n_in,
                              void* d_out, int out_size, void* d_ws, size_t ws_size,
                              hipStream_t stream) {
  const float* x   = (const float*)d_in[0];
  const int*  eidx = (const int*)d_in[1];
  const float* ew  = (const float*)d_in[2];
  const float* Wi  = (const float*)d_in[3];
  const float* bi  = (const float*)d_in[4];
  const float* Wc[12]; const float* bc[12];
  for (int i = 0; i < 12; ++i) {
    Wc[i] = (const float*)d_in[5 + 2 * i];
    bc[i] = (const float*)d_in[6 + 2 * i];
  }
  const float* Wm0 = (const float*)d_in[29]; const float* bm0 = (const float*)d_in[30];
  const float* Wm1 = (const float*)d_in[31]; const float* bm1 = (const float*)d_in[32];
  const float* Wf  = (const float*)d_in[33]; const float* bf  = (const float*)d_in[34];
  float* out = (float*)d_out;

  const int* src = eidx;        // edge_index[0]
  const int* dst = eidx + kE;   // edge_index[1]

  float* wsf = (float*)d_ws;
  size_t off = 0;
  float*     dinv = wsf + off;              off += PAD_N;
  float*     Weff = wsf + off;              off += 128 * 32;
  float*     beff = wsf + off;              off += 64;
  int*       cnt  = (int*)(wsf + off);      off += PAD_N;          // cnt+ecw
  unsigned*  ecw  = (unsigned*)(wsf + off); off += (size_t)PAD_N * kCAP;  // contiguous (prep zeroes both)
  _Float16*  B16  = (_Float16*)(wsf + off); off += (size_t)PAD_N * 16;
  _Float16*  C16  = (_Float16*)(wsf + off); off += (size_t)PAD_N * 16;
  unsigned*  cwe  = (unsigned*)(wsf + off); off += kE;             // 6.4 MB

  const int dgb  = PAD_N / 4;       // 12544 (deg grid, bucket rows)
  const int sb32 = PAD_N / 8;       // 6272  (2 rows/wave; mult of 8)
  const int sb16 = PAD_N / 16;      // 3136  (4 rows/wave; mult of 8)
  const int sb8  = PAD_N / 32;      // 1568  (8 rows/wave; mult of 8)

  prep<<<PREPG, 256, 0, stream>>>(cnt, Wi, bi, Wc[0], Weff, beff, src, ew, cwe);
  build_cnt_gemm0<<<NBG + 8 * E8B, 256, 0, stream>>>(dst, cwe, cnt, ecw,
                                                     x, Weff, beff, B16, E4, kN);
  deg_dinv_wave<<<dgb, 256, 0, stream>>>(cnt, ecw, dinv);

  spmm_fused<32, 32, false, true ><<<sb32, 256, 0, stream>>>(B16, cnt, ecw, dinv, bc[0], Wc[1], C16, nullptr, nullptr, nullptr, nullptr, nullptr, nullptr, kN);
  spmm_fused<32, 32, false, false><<<sb32, 256, 0, stream>>>(C16, cnt, ecw, dinv, bc[1], Wc[2], B16, nullptr, nullptr, nullptr, nullptr, nullptr, nullptr, kN);
  spmm_fused<32, 32, false, false><<<sb32, 256, 0, stream>>>(B16, cnt, ecw, dinv, bc[2], Wc[3], C16, nullptr, nullptr, nullptr, nullptr, nullptr, nullptr, kN);
  spmm_fused<32, 16, false, false><<<sb32, 256, 0, stream>>>(C16, cnt, ecw, dinv, bc[3], Wc[4], B16, nullptr, nullptr, nullptr, nullptr, nullptr, nullptr, kN);
  spmm_fused<16, 16, false, false><<<sb16, 256, 0, stream>>>(B16, cnt, ecw, dinv, bc[4], Wc[5], C16, nullptr, nullptr, nullptr, nullptr, nullptr, nullptr, kN);
  spmm_fused<16, 16, false, false><<<sb16, 256, 0, stream>>>(C16, cnt, ecw, dinv, bc[5], Wc[6], B16, nullptr, nullptr, nullptr, nullptr, nullptr, nullptr, kN);
  spmm_fused<16, 16, false, false><<<sb16, 256, 0, stream>>>(B16, cnt, ecw, dinv, bc[6], Wc[7], C16, nullptr, nullptr, nullptr, nullptr, nullptr, nullptr, kN);
  spmm_fused<16, 8, false, false><<<sb16, 256, 0, stream>>>(C16, cnt, ecw, dinv, bc[7], Wc[8], B16, nullptr, nullptr, nullptr, nullptr, nullptr, nullptr, kN);
  spmm_fused<8, 8, false, false><<<sb8, 256, 0, stream>>>(B16, cnt, ecw, dinv, bc[8], Wc[9], C16, nullptr, nullptr, nullptr, nullptr, nullptr, nullptr, kN);
  spmm_fused<8, 8, false, false><<<sb8, 256, 0, stream>>>(C16, cnt, ecw, dinv, bc[9], Wc[10], B16, nullptr, nullptr, nullptr, nullptr, nullptr, nullptr, kN);
  spmm_fused<8, 8, false, false><<<sb8, 256, 0, stream>>>(B16, cnt, ecw, dinv, bc[10], Wc[11], C16, nullptr, nullptr, nullptr, nullptr, nullptr, nullptr, kN);
  spmm_fused<8, 0, true, false><<<sb8, 256, 0, stream>>>(C16, cnt, ecw, dinv, bc[11], nullptr, out, Wm0, bm0, Wm1, bm1, Wf, bf, kN);
}